// Round 1
// baseline (1498.353 us; speedup 1.0000x reference)
//
#include <hip/hip_runtime.h>
#include <hip/hip_bf16.h>

#define DIV_UP(a,b) (((a)+(b)-1)/(b))

// ---------- bf16 helpers (manual, deterministic RNE) ----------
static __device__ __forceinline__ unsigned short f2bf(float v) {
    unsigned u = __builtin_bit_cast(unsigned, v);
    u += 0x7fffu + ((u >> 16) & 1u);
    return (unsigned short)(u >> 16);
}
static __device__ __forceinline__ float bf2f(unsigned short u) {
    return __builtin_bit_cast(float, (unsigned)u << 16);
}

// ---------- fp32 tiled GEMM, bf16 output: C[M,N] = A[M,K] @ B[K,N] ----------
// BM=BN=64, BK=16, 256 threads, 4x4 microtile per thread.
__global__ __launch_bounds__(256) void gemm_bf16out(
    const float* __restrict__ A, const float* __restrict__ B,
    unsigned short* __restrict__ C, int M, int N, int K) {
    __shared__ float As[16][64];   // As[k][m]
    __shared__ float Bs[16][64];   // Bs[k][n]
    const int tid = threadIdx.x;
    const int m0 = blockIdx.y * 64, n0 = blockIdx.x * 64;
    const int tm = (tid >> 4) << 2;
    const int tn = (tid & 15) << 2;
    const int ar = tid >> 2, ac4 = (tid & 3) << 2;   // A tile: row ar, k-offset ac4
    const int br = tid >> 4, bc4 = (tid & 15) << 2;  // B tile: k-row br, n-offset bc4
    float acc[4][4] = {};
    for (int k0 = 0; k0 < K; k0 += 16) {
        float4 av = make_float4(0.f, 0.f, 0.f, 0.f);
        int am = m0 + ar;
        if (am < M) av = *(const float4*)(A + (size_t)am * K + k0 + ac4);
        float4 bv = *(const float4*)(B + (size_t)(k0 + br) * N + n0 + bc4);
        As[ac4 + 0][ar] = av.x; As[ac4 + 1][ar] = av.y;
        As[ac4 + 2][ar] = av.z; As[ac4 + 3][ar] = av.w;
        *(float4*)(&Bs[br][bc4]) = bv;
        __syncthreads();
#pragma unroll
        for (int kk = 0; kk < 16; ++kk) {
            float4 a4 = *(const float4*)(&As[kk][tm]);
            float4 b4 = *(const float4*)(&Bs[kk][tn]);
            float a[4] = {a4.x, a4.y, a4.z, a4.w};
            float b[4] = {b4.x, b4.y, b4.z, b4.w};
#pragma unroll
            for (int i = 0; i < 4; ++i)
#pragma unroll
                for (int j = 0; j < 4; ++j)
                    acc[i][j] = fmaf(a[i], b[j], acc[i][j]);
        }
        __syncthreads();
    }
#pragma unroll
    for (int i = 0; i < 4; ++i) {
        int m = m0 + tm + i;
        if (m < M) {
            ushort4 pk;
            pk.x = f2bf(acc[i][0]); pk.y = f2bf(acc[i][1]);
            pk.z = f2bf(acc[i][2]); pk.w = f2bf(acc[i][3]);
            *(ushort4*)(C + (size_t)m * N + n0 + tn) = pk;
        }
    }
}

// ---------- CSR build (group edges by dst) ----------
__global__ void count_kernel(const int* __restrict__ dst, int E, int* __restrict__ cnt) {
    int e = blockIdx.x * blockDim.x + threadIdx.x;
    if (e < E) atomicAdd(&cnt[dst[e]], 1);
}

__global__ __launch_bounds__(1024) void scan_kernel(const int* __restrict__ cnt, int N,
                                                    int* __restrict__ off, int* __restrict__ cur) {
    __shared__ int part[1024];
    int t = threadIdx.x;
    int per = (N + 1023) >> 10;
    int base = t * per;
    int s = 0;
    for (int i = 0; i < per; ++i) { int idx = base + i; if (idx < N) s += cnt[idx]; }
    part[t] = s;
    __syncthreads();
    for (int d2 = 1; d2 < 1024; d2 <<= 1) {
        int v = (t >= d2) ? part[t - d2] : 0;
        __syncthreads();
        part[t] += v;
        __syncthreads();
    }
    int pre = (t == 0) ? 0 : part[t - 1];
    for (int i = 0; i < per; ++i) {
        int idx = base + i;
        if (idx < N) { off[idx] = pre; cur[idx] = pre; pre += cnt[idx]; }
    }
    if (t == 1023) off[N] = part[1023];
}

__global__ void fill_kernel(const int* __restrict__ src, const int* __restrict__ dst, int E,
                            int* __restrict__ cur, int2* __restrict__ edges) {
    int e = blockIdx.x * blockDim.x + threadIdx.x;
    if (e < E) {
        int p = atomicAdd(&cur[dst[e]], 1);
        edges[p] = make_int2(src[e], e);
    }
}

// ---------- per-edge attention logits (ea@We fused, computed on the fly) ----------
template <int H, int C, bool HASE>
__global__ __launch_bounds__(256) void logit_kernel(
    const unsigned short* __restrict__ xl, const unsigned short* __restrict__ xr,
    const float* __restrict__ ea, const float* __restrict__ We,
    const float* __restrict__ att,
    const int* __restrict__ src, const int* __restrict__ dst, int E,
    float* __restrict__ logit) {
    constexpr int D = H * C;
    constexpr int CH = D / 64;   // 64-channel chunks
    constexpr int CPH = C / 64;  // chunks per head
    int e = (int)(((size_t)blockIdx.x * blockDim.x + threadIdx.x) >> 6);
    int lane = threadIdx.x & 63;
    if (e >= E) return;
    int s = src[e], d = dst[e];
    const unsigned short* xls = xl + (size_t)s * D;
    const unsigned short* xrd = xr + (size_t)d * D;
    float ev[HASE ? 8 : 1];
    if (HASE) {
#pragma unroll
        for (int k = 0; k < 8; ++k) ev[k] = ea[(size_t)e * 8 + k];
    }
    float acc[H] = {};
#pragma unroll
    for (int ch = 0; ch < CH; ++ch) {
        int c = ch * 64 + lane;
        float v = bf2f(xls[c]) + bf2f(xrd[c]);
        if (HASE) {
#pragma unroll
            for (int k = 0; k < 8; ++k) v = fmaf(ev[k], We[k * D + c], v);
        }
        v = v > 0.f ? v : 0.2f * v;  // leaky_relu(0.2)
        acc[ch / CPH] = fmaf(att[c], v, acc[ch / CPH]);
    }
#pragma unroll
    for (int h = 0; h < H; ++h) {
        float r = acc[h];
#pragma unroll
        for (int o = 32; o; o >>= 1) r += __shfl_xor(r, o, 64);
        if (lane == h) logit[(size_t)e * H + h] = r;
    }
}

// ---------- per-(node,head) softmax stats via CSR ----------
__global__ void softmax_stats(const float* __restrict__ logit,
                              const int2* __restrict__ edges,
                              const int* __restrict__ off,
                              int N, int H, float* __restrict__ mx, float* __restrict__ den) {
    int i = blockIdx.x * blockDim.x + threadIdx.x;
    if (i >= N * H) return;
    int node = i / H, h = i - node * H;
    int a = off[node], b = off[node + 1];
    float m = -3.0e38f;
    for (int j = a; j < b; ++j) m = fmaxf(m, logit[(size_t)edges[j].y * H + h]);
    float s = 0.f;
    for (int j = a; j < b; ++j) s += __expf(logit[(size_t)edges[j].y * H + h] - m);
    mx[i] = m;
    den[i] = s;
}

// ---------- aggregation: out[i] = sum_j alpha_ij * xl[src_j]  (+bias, opt relu) ----------
template <int H, int C, bool RELU>
__global__ __launch_bounds__(256) void aggregate_kernel(
    const unsigned short* __restrict__ xl, const float* __restrict__ logit,
    const float* __restrict__ mx, const float* __restrict__ den,
    const int2* __restrict__ edges, const int* __restrict__ off,
    const float* __restrict__ bias, float* __restrict__ out, int N) {
    constexpr int D = H * C, CH = D / 64, CPH = C / 64;
    int gw = (int)(((size_t)blockIdx.x * blockDim.x + threadIdx.x) >> 6);
    int lane = threadIdx.x & 63;
    int node = gw / CH, ch = gw - node * CH;
    if (node >= N) return;
    int h = ch / CPH;
    int c = ch * 64 + lane;
    float m = mx[node * H + h];
    float inv = 1.f / (den[node * H + h] + 1e-16f);
    float acc = 0.f;
    int a = off[node], b = off[node + 1];
    for (int j = a; j < b; ++j) {
        int2 se = edges[j];
        float al = __expf(logit[(size_t)se.y * H + h] - m) * inv;
        acc = fmaf(al, bf2f(xl[(size_t)se.x * D + c]), acc);
    }
    float r = acc + bias[c];
    if (RELU) r = fmaxf(r, 0.f);
    out[(size_t)node * D + c] = r;
}

// ---------- head: last-node gather + 2-layer MLP ----------
__global__ void lastidx_kernel(const int* __restrict__ nn, int G, int* __restrict__ last) {
    int t = blockIdx.x * blockDim.x + threadIdx.x;
    if (t < G) {
        int s = 0;
        for (int k = 0; k <= t; ++k) s += nn[k];
        last[t] = s - 1;
    }
}

__global__ void mlp_kernel(const float* __restrict__ h3, const int* __restrict__ last,
                           const float* __restrict__ Wfc1, const float* __restrict__ bfc1,
                           const float* __restrict__ Wfc2, const float* __restrict__ bfc2,
                           float* __restrict__ out, int G) {
    int g = blockIdx.x, t = threadIdx.x;  // 64 threads
    const float* row = h3 + (size_t)last[g] * 384;
    float z = bfc1[t];
    for (int k = 0; k < 384; ++k) z = fmaf(row[k], Wfc1[k * 64 + t], z);
    z = fmaxf(z, 0.f);
    float v = z * Wfc2[t];
#pragma unroll
    for (int o = 32; o; o >>= 1) v += __shfl_xor(v, o, 64);
    if (t == 0) out[g] = v + bfc2[0];
}

extern "C" void kernel_launch(void* const* d_in, const int* in_sizes, int n_in,
                              void* d_out, int out_size, void* d_ws, size_t ws_size,
                              hipStream_t stream) {
    const float* x    = (const float*)d_in[0];
    const float* ea   = (const float*)d_in[1];
    const float* Wl1  = (const float*)d_in[2];
    const float* Wr1  = (const float*)d_in[3];
    const float* We1  = (const float*)d_in[4];
    const float* att1 = (const float*)d_in[5];
    const float* b1   = (const float*)d_in[6];
    const float* Wl2  = (const float*)d_in[7];
    const float* Wr2  = (const float*)d_in[8];
    const float* We2  = (const float*)d_in[9];
    const float* att2 = (const float*)d_in[10];
    const float* b2   = (const float*)d_in[11];
    const float* Wlp  = (const float*)d_in[12];
    const float* Wrp  = (const float*)d_in[13];
    const float* attp = (const float*)d_in[14];
    const float* bp   = (const float*)d_in[15];
    const float* Wfc1 = (const float*)d_in[16];
    const float* bfc1 = (const float*)d_in[17];
    const float* Wfc2 = (const float*)d_in[18];
    const float* bfc2 = (const float*)d_in[19];
    const int* ei     = (const int*)d_in[20];
    const int* eim    = (const int*)d_in[21];
    const int* nn     = (const int*)d_in[22];

    const int N = in_sizes[0] / 64;   // 20000
    const int E = in_sizes[20] / 2;   // 160000
    const int G = in_sizes[22];       // 100
    const int* src1 = ei,  *dst1 = ei + E;
    const int* srcm = eim, *dstm = eim + E;

    // ---- workspace layout (~170 MB peak) ----
    char* w = (char*)d_ws;
    size_t o = 0;
    auto alloc = [&](size_t b) { size_t r = o; o += (b + 255) & ~(size_t)255; return r; };
    unsigned short* xl = (unsigned short*)(w + alloc((size_t)N * 1024 * 2)); // xl1/xl2/xl3
    unsigned short* xr = (unsigned short*)(w + alloc((size_t)N * 1024 * 2)); // xr1/xr2/xr3
    char* hbig = w + alloc((size_t)N * 1024 * 4);                            // h1; then h2; h3 at +32MB
    float* h1 = (float*)hbig;
    float* h2 = (float*)hbig;
    float* h3 = (float*)(hbig + 33554432);
    float* logit = (float*)(w + alloc((size_t)E * 6 * 4));
    float* mx    = (float*)(w + alloc((size_t)N * 6 * 4));
    float* den   = (float*)(w + alloc((size_t)N * 6 * 4));
    int*  cnt   = (int*)(w + alloc((size_t)N * 4));
    int*  off   = (int*)(w + alloc((size_t)(N + 1) * 4));
    int*  cur   = (int*)(w + alloc((size_t)N * 4));
    int2* edges = (int2*)(w + alloc((size_t)E * 8));
    int*  last  = (int*)(w + alloc(512));
    (void)ws_size; (void)n_in; (void)out_size;

    dim3 blk(256);

    // ---- CSR for edge_index (used by layers 1 & 2) ----
    hipMemsetAsync(cnt, 0, (size_t)N * 4, stream);
    count_kernel<<<DIV_UP(E, 256), blk, 0, stream>>>(dst1, E, cnt);
    scan_kernel<<<1, 1024, 0, stream>>>(cnt, N, off, cur);
    fill_kernel<<<DIV_UP(E, 256), blk, 0, stream>>>(src1, dst1, E, cur, edges);

    // ---- Layer 1: H=4, C=256, D=1024 ----
    gemm_bf16out<<<dim3(1024 / 64, DIV_UP(N, 64)), blk, 0, stream>>>(x, Wl1, xl, N, 1024, 64);
    gemm_bf16out<<<dim3(1024 / 64, DIV_UP(N, 64)), blk, 0, stream>>>(x, Wr1, xr, N, 1024, 64);
    logit_kernel<4, 256, true><<<DIV_UP(E * 64, 256), blk, 0, stream>>>(xl, xr, ea, We1, att1, src1, dst1, E, logit);
    softmax_stats<<<DIV_UP(N * 4, 256), blk, 0, stream>>>(logit, edges, off, N, 4, mx, den);
    aggregate_kernel<4, 256, true><<<DIV_UP(N * 16 * 64, 256), blk, 0, stream>>>(xl, logit, mx, den, edges, off, b1, h1, N);

    // ---- Layer 2: H=4, C=64, D=256 ----
    gemm_bf16out<<<dim3(256 / 64, DIV_UP(N, 64)), blk, 0, stream>>>(h1, Wl2, xl, N, 256, 1024);
    gemm_bf16out<<<dim3(256 / 64, DIV_UP(N, 64)), blk, 0, stream>>>(h1, Wr2, xr, N, 256, 1024);
    logit_kernel<4, 64, true><<<DIV_UP(E * 64, 256), blk, 0, stream>>>(xl, xr, ea, We2, att2, src1, dst1, E, logit);
    softmax_stats<<<DIV_UP(N * 4, 256), blk, 0, stream>>>(logit, edges, off, N, 4, mx, den);
    aggregate_kernel<4, 64, true><<<DIV_UP(N * 4 * 64, 256), blk, 0, stream>>>(xl, logit, mx, den, edges, off, b2, h2, N);

    // ---- CSR for edge_index_master (layer 3) ----
    hipMemsetAsync(cnt, 0, (size_t)N * 4, stream);
    count_kernel<<<DIV_UP(E, 256), blk, 0, stream>>>(dstm, E, cnt);
    scan_kernel<<<1, 1024, 0, stream>>>(cnt, N, off, cur);
    fill_kernel<<<DIV_UP(E, 256), blk, 0, stream>>>(srcm, dstm, E, cur, edges);

    // ---- Layer 3: H=6, C=64, D=384, no edge_attr, no relu ----
    gemm_bf16out<<<dim3(384 / 64, DIV_UP(N, 64)), blk, 0, stream>>>(h2, Wlp, xl, N, 384, 256);
    gemm_bf16out<<<dim3(384 / 64, DIV_UP(N, 64)), blk, 0, stream>>>(h2, Wrp, xr, N, 384, 256);
    logit_kernel<6, 64, false><<<DIV_UP(E * 64, 256), blk, 0, stream>>>(xl, xr, nullptr, nullptr, attp, srcm, dstm, E, logit);
    softmax_stats<<<DIV_UP(N * 6, 256), blk, 0, stream>>>(logit, edges, off, N, 6, mx, den);
    aggregate_kernel<6, 64, false><<<DIV_UP(N * 6 * 64, 256), blk, 0, stream>>>(xl, logit, mx, den, edges, off, bp, h3, N);

    // ---- head ----
    lastidx_kernel<<<1, 128, 0, stream>>>(nn, G, last);
    mlp_kernel<<<G, 64, 0, stream>>>(h3, last, Wfc1, bfc1, Wfc2, bfc2, (float*)d_out, G);
}

// Round 2
// 751.880 us; speedup vs baseline: 1.9928x; 1.9928x over previous
//
#include <hip/hip_runtime.h>
#include <hip/hip_bf16.h>

#define DIV_UP(a,b) (((a)+(b)-1)/(b))

typedef __attribute__((ext_vector_type(8))) short short8;
typedef __attribute__((ext_vector_type(4))) float floatx4;

// ---------- bf16 helpers (manual, deterministic RNE) ----------
static __device__ __forceinline__ unsigned short f2bf(float v) {
    unsigned u = __builtin_bit_cast(unsigned, v);
    u += 0x7fffu + ((u >> 16) & 1u);
    return (unsigned short)(u >> 16);
}
static __device__ __forceinline__ float bf2f(unsigned u16) {
    return __builtin_bit_cast(float, u16 << 16);
}

// load CPL bf16 (4B-aligned at least) -> float
template <int CPL>
static __device__ __forceinline__ void load_bf16v(const unsigned short* p, float* d) {
    if constexpr (CPL == 8) {
        uint4 v = *(const uint4*)p;
        d[0] = bf2f(v.x & 0xffffu); d[1] = bf2f(v.x >> 16);
        d[2] = bf2f(v.y & 0xffffu); d[3] = bf2f(v.y >> 16);
        d[4] = bf2f(v.z & 0xffffu); d[5] = bf2f(v.z >> 16);
        d[6] = bf2f(v.w & 0xffffu); d[7] = bf2f(v.w >> 16);
    } else if constexpr (CPL == 4) {
        uint2 v = *(const uint2*)p;
        d[0] = bf2f(v.x & 0xffffu); d[1] = bf2f(v.x >> 16);
        d[2] = bf2f(v.y & 0xffffu); d[3] = bf2f(v.y >> 16);
    } else if constexpr (CPL == 6) {
        const unsigned* q = (const unsigned*)p;
        unsigned a = q[0], b = q[1], c = q[2];
        d[0] = bf2f(a & 0xffffu); d[1] = bf2f(a >> 16);
        d[2] = bf2f(b & 0xffffu); d[3] = bf2f(b >> 16);
        d[4] = bf2f(c & 0xffffu); d[5] = bf2f(c >> 16);
    }
}

template <int HW>
static __device__ __forceinline__ float pick(const float (&a)[HW], int i) {
    float r = a[0];
#pragma unroll
    for (int t = 1; t < HW; ++t) r = (i == t) ? a[t] : r;
    return r;
}

// ---------- weight prep: W[K,N] fp32 -> Wt[N,K] bf16 ----------
__global__ void cvt_transpose(const float* __restrict__ W, int K, int Nn,
                              unsigned short* __restrict__ Wt) {
    int id = blockIdx.x * blockDim.x + threadIdx.x;
    if (id >= K * Nn) return;
    int k = id % K, n = id / K;
    Wt[(size_t)n * K + k] = f2bf(W[(size_t)k * Nn + n]);
}

__global__ void cvt_bf16(const float* __restrict__ in, unsigned short* __restrict__ out, int n) {
    int id = blockIdx.x * blockDim.x + threadIdx.x;
    if (id < n) out[id] = f2bf(in[id]);
}

// ---------- MFMA bf16 GEMM: C[M,Ntot] = A[M,K] @ Bt[Ntot,K]^T  (all bf16, fp32 acc) ----------
// 128x128 tile, BK=32, 4 waves in 2x2, each 64x64 (16 mfma : 8 ds_read_b128).
__global__ __launch_bounds__(256) void gemm_mfma(
    const unsigned short* __restrict__ A, const unsigned short* __restrict__ Bt,
    unsigned short* __restrict__ C, int M, int Ntot, int K) {
    constexpr int LDA = 40;  // +8 pad: 80B row stride (16B-aligned, 2-way bank max)
    __shared__ unsigned short As[128 * LDA];
    __shared__ unsigned short Bs[128 * LDA];
    const int tid = threadIdx.x;
    const int m0 = blockIdx.y * 128, n0 = blockIdx.x * 128;
    const int wave = tid >> 6, lane = tid & 63;
    const int wm = (wave >> 1) * 64, wn = (wave & 1) * 64;
    const int r15 = lane & 15, quad = lane >> 4;
    const int sr = tid >> 1, skc = tid & 1;  // staging: row 0..127, 32B half 0..1
    floatx4 acc[4][4];
#pragma unroll
    for (int i = 0; i < 4; ++i)
#pragma unroll
        for (int j = 0; j < 4; ++j) acc[i][j] = (floatx4)0.f;

    for (int k0 = 0; k0 < K; k0 += 32) {
        uint4 a0 = make_uint4(0, 0, 0, 0), a1 = make_uint4(0, 0, 0, 0);
        int am = m0 + sr;
        if (am < M) {
            const unsigned short* ap = A + (size_t)am * K + k0 + skc * 16;
            a0 = *(const uint4*)ap;
            a1 = *(const uint4*)(ap + 8);
        }
        const unsigned short* bp = Bt + (size_t)(n0 + sr) * K + k0 + skc * 16;
        uint4 b0 = *(const uint4*)bp;
        uint4 b1 = *(const uint4*)(bp + 8);
        *(uint4*)(&As[sr * LDA + skc * 16]) = a0;
        *(uint4*)(&As[sr * LDA + skc * 16 + 8]) = a1;
        *(uint4*)(&Bs[sr * LDA + skc * 16]) = b0;
        *(uint4*)(&Bs[sr * LDA + skc * 16 + 8]) = b1;
        __syncthreads();
        short8 af[4], bfr[4];
#pragma unroll
        for (int i = 0; i < 4; ++i)
            af[i] = *(const short8*)(&As[(wm + i * 16 + r15) * LDA + quad * 8]);
#pragma unroll
        for (int j = 0; j < 4; ++j)
            bfr[j] = *(const short8*)(&Bs[(wn + j * 16 + r15) * LDA + quad * 8]);
#pragma unroll
        for (int i = 0; i < 4; ++i)
#pragma unroll
            for (int j = 0; j < 4; ++j)
                acc[i][j] = __builtin_amdgcn_mfma_f32_16x16x32_bf16(af[i], bfr[j], acc[i][j], 0, 0, 0);
        __syncthreads();
    }
    // C/D layout: col = lane&15, row = quad*4 + reg
#pragma unroll
    for (int i = 0; i < 4; ++i)
#pragma unroll
        for (int j = 0; j < 4; ++j)
#pragma unroll
            for (int r = 0; r < 4; ++r) {
                int m = m0 + wm + i * 16 + quad * 4 + r;
                int n = n0 + wn + j * 16 + r15;
                if (m < M) C[(size_t)m * Ntot + n] = f2bf(acc[i][j][r]);
            }
}

// ---------- CSR build (group edges by dst) ----------
__global__ void count_kernel(const int* __restrict__ dst, int E, int* __restrict__ cnt) {
    int e = blockIdx.x * blockDim.x + threadIdx.x;
    if (e < E) atomicAdd(&cnt[dst[e]], 1);
}

__global__ __launch_bounds__(1024) void scan_kernel(const int* __restrict__ cnt, int N,
                                                    int* __restrict__ off, int* __restrict__ cur) {
    __shared__ int part[1024];
    int t = threadIdx.x;
    int per = (N + 1023) >> 10;
    int base = t * per;
    int s = 0;
    for (int i = 0; i < per; ++i) { int idx = base + i; if (idx < N) s += cnt[idx]; }
    part[t] = s;
    __syncthreads();
    for (int d2 = 1; d2 < 1024; d2 <<= 1) {
        int v = (t >= d2) ? part[t - d2] : 0;
        __syncthreads();
        part[t] += v;
        __syncthreads();
    }
    int pre = (t == 0) ? 0 : part[t - 1];
    for (int i = 0; i < per; ++i) {
        int idx = base + i;
        if (idx < N) { off[idx] = pre; cur[idx] = pre; pre += cnt[idx]; }
    }
    if (t == 1023) off[N] = part[1023];
}

__global__ void fill_kernel(const int* __restrict__ src, const int* __restrict__ dst, int E,
                            int* __restrict__ cur, int2* __restrict__ edges) {
    int e = blockIdx.x * blockDim.x + threadIdx.x;
    if (e < E) {
        int p = atomicAdd(&cur[dst[e]], 1);
        edges[p] = make_int2(src[e], e);
    }
}

// ---------- fused GATv2 edge phase: logits + online softmax + aggregation ----------
// One node handled by WPN waves; lane owns CPL contiguous channels.
// xlr is [N, 2D] bf16: cols [0,D) = Wl-transform (xl), [D,2D) = Wr-transform (xr).
template <int H, int C, int WPN, bool HASE, bool RELU, bool OUTBF16>
__global__ __launch_bounds__(256) void attn_fused(
    const unsigned short* __restrict__ xlr, const float* __restrict__ ea,
    const float* __restrict__ We, const float* __restrict__ att,
    const int2* __restrict__ edges, const int* __restrict__ off,
    const float* __restrict__ bias, void* __restrict__ outp, int N) {
    constexpr int D = H * C;
    constexpr int CPW = D / WPN;   // channels per wave
    constexpr int CPL = CPW / 64;  // channels per lane
    constexpr int HW = H / WPN;    // heads per wave
    constexpr int NPB = 4 / WPN;   // nodes per 256-thread block
    const int wid = threadIdx.x >> 6, lane = threadIdx.x & 63;
    const int node = blockIdx.x * NPB + wid / WPN;
    const int wv = wid % WPN;
    if (node >= N) return;
    const int c0 = wv * CPW + lane * CPL;  // global channel base for this lane
    const int hb = wv * HW;                // first head of this wave

    float xr_r[CPL], att_r[CPL];
    load_bf16v<CPL>(xlr + (size_t)node * (2 * D) + D + c0, xr_r);
#pragma unroll
    for (int c = 0; c < CPL; ++c) att_r[c] = att[c0 + c];
    float we_r[HASE ? 8 : 1][CPL];
    if constexpr (HASE) {
#pragma unroll
        for (int k = 0; k < 8; ++k)
#pragma unroll
            for (int c = 0; c < CPL; ++c) we_r[k][c] = We[k * D + c0 + c];
    }
    int hl_c[CPL];  // head-local index per channel (constant-unrolled accesses only)
#pragma unroll
    for (int c = 0; c < CPL; ++c) hl_c[c] = (c0 + c) / C - hb;

    float m_h[HW], l_h[HW], acc[CPL];
#pragma unroll
    for (int h = 0; h < HW; ++h) { m_h[h] = -1e30f; l_h[h] = 0.f; }
#pragma unroll
    for (int c = 0; c < CPL; ++c) acc[c] = 0.f;

    const int jb = off[node], je = off[node + 1];
    for (int j = jb; j < je; ++j) {
        int2 se = edges[j];
        float xv[CPL];
        load_bf16v<CPL>(xlr + (size_t)se.x * (2 * D) + c0, xv);
        float lg[HW];
#pragma unroll
        for (int h = 0; h < HW; ++h) lg[h] = 0.f;
        if constexpr (HASE) {
            float ev[8];
#pragma unroll
            for (int k = 0; k < 8; ++k) ev[k] = ea[(size_t)se.y * 8 + k];
#pragma unroll
            for (int c = 0; c < CPL; ++c) {
                float z = xv[c] + xr_r[c];
#pragma unroll
                for (int k = 0; k < 8; ++k) z = fmaf(ev[k], we_r[k][c], z);
                z = z > 0.f ? z : 0.2f * z;
                float v = att_r[c] * z;
#pragma unroll
                for (int h = 0; h < HW; ++h) if (hl_c[c] == h) lg[h] += v;
            }
        } else {
#pragma unroll
            for (int c = 0; c < CPL; ++c) {
                float z = xv[c] + xr_r[c];
                z = z > 0.f ? z : 0.2f * z;
                float v = att_r[c] * z;
#pragma unroll
                for (int h = 0; h < HW; ++h) if (hl_c[c] == h) lg[h] += v;
            }
        }
#pragma unroll
        for (int h = 0; h < HW; ++h) {
#pragma unroll
            for (int o = 32; o; o >>= 1) lg[h] += __shfl_xor(lg[h], o, 64);
        }
        float sc[HW], p[HW];
#pragma unroll
        for (int h = 0; h < HW; ++h) {
            float mn = fmaxf(m_h[h], lg[h]);
            sc[h] = __expf(m_h[h] - mn);
            p[h] = __expf(lg[h] - mn);
            m_h[h] = mn;
            l_h[h] = fmaf(l_h[h], sc[h], p[h]);
        }
#pragma unroll
        for (int c = 0; c < CPL; ++c) {
            float scl = pick<HW>(sc, hl_c[c]);
            float pl = pick<HW>(p, hl_c[c]);
            acc[c] = fmaf(acc[c], scl, pl * xv[c]);
        }
    }
#pragma unroll
    for (int c = 0; c < CPL; ++c) {
        float inv = 1.f / (pick<HW>(l_h, hl_c[c]) + 1e-16f);
        float r = fmaf(acc[c], inv, bias[c0 + c]);
        if constexpr (RELU) r = fmaxf(r, 0.f);
        if constexpr (OUTBF16)
            ((unsigned short*)outp)[(size_t)node * D + c0 + c] = f2bf(r);
        else
            ((float*)outp)[(size_t)node * D + c0 + c] = r;
    }
}

// ---------- head: last-node gather + 2-layer MLP ----------
__global__ void lastidx_kernel(const int* __restrict__ nn, int G, int* __restrict__ last) {
    int t = blockIdx.x * blockDim.x + threadIdx.x;
    if (t < G) {
        int s = 0;
        for (int k = 0; k <= t; ++k) s += nn[k];
        last[t] = s - 1;
    }
}

__global__ void mlp_kernel(const float* __restrict__ h3, const int* __restrict__ last,
                           const float* __restrict__ Wfc1, const float* __restrict__ bfc1,
                           const float* __restrict__ Wfc2, const float* __restrict__ bfc2,
                           float* __restrict__ out, int G) {
    int g = blockIdx.x, t = threadIdx.x;  // 64 threads
    const float* row = h3 + (size_t)last[g] * 384;
    float z = bfc1[t];
    for (int k = 0; k < 384; ++k) z = fmaf(row[k], Wfc1[k * 64 + t], z);
    z = fmaxf(z, 0.f);
    float v = z * Wfc2[t];
#pragma unroll
    for (int o = 32; o; o >>= 1) v += __shfl_xor(v, o, 64);
    if (t == 0) out[g] = v + bfc2[0];
}

extern "C" void kernel_launch(void* const* d_in, const int* in_sizes, int n_in,
                              void* d_out, int out_size, void* d_ws, size_t ws_size,
                              hipStream_t stream) {
    const float* x    = (const float*)d_in[0];
    const float* ea   = (const float*)d_in[1];
    const float* Wl1  = (const float*)d_in[2];
    const float* Wr1  = (const float*)d_in[3];
    const float* We1  = (const float*)d_in[4];
    const float* att1 = (const float*)d_in[5];
    const float* b1   = (const float*)d_in[6];
    const float* Wl2  = (const float*)d_in[7];
    const float* Wr2  = (const float*)d_in[8];
    const float* We2  = (const float*)d_in[9];
    const float* att2 = (const float*)d_in[10];
    const float* b2   = (const float*)d_in[11];
    const float* Wlp  = (const float*)d_in[12];
    const float* Wrp  = (const float*)d_in[13];
    const float* attp = (const float*)d_in[14];
    const float* bp   = (const float*)d_in[15];
    const float* Wfc1 = (const float*)d_in[16];
    const float* bfc1 = (const float*)d_in[17];
    const float* Wfc2 = (const float*)d_in[18];
    const float* bfc2 = (const float*)d_in[19];
    const int* ei     = (const int*)d_in[20];
    const int* eim    = (const int*)d_in[21];
    const int* nn     = (const int*)d_in[22];

    const int N = in_sizes[0] / 64;   // 20000
    const int E = in_sizes[20] / 2;   // 160000
    const int G = in_sizes[22];       // 100
    const int* src1 = ei,  *dst1 = ei + E;
    const int* srcm = eim, *dstm = eim + E;

    // ---- workspace layout (~156 MB peak) ----
    char* w = (char*)d_ws;
    size_t o = 0;
    auto alloc = [&](size_t b) { size_t r = o; o += (b + 255) & ~(size_t)255; return r; };
    // region R1: xlr1 (80MB); reused later for xlr3 (30MB) + h3 (30MB)
    char* R1 = w + alloc((size_t)N * 2048 * 2);
    unsigned short* xlr1 = (unsigned short*)R1;
    unsigned short* xlr3 = (unsigned short*)R1;
    float* h3 = (float*)(R1 + (size_t)N * 768 * 2 + 256);
    unsigned short* h1   = (unsigned short*)(w + alloc((size_t)N * 1024 * 2));
    unsigned short* xlr2 = (unsigned short*)(w + alloc((size_t)N * 512 * 2));
    unsigned short* h2   = (unsigned short*)(w + alloc((size_t)N * 256 * 2));
    unsigned short* xbf  = (unsigned short*)(w + alloc((size_t)N * 64 * 2));
    unsigned short* wt1  = (unsigned short*)(w + alloc((size_t)2048 * 64 * 2));
    unsigned short* wt2  = (unsigned short*)(w + alloc((size_t)512 * 1024 * 2));
    unsigned short* wt3  = (unsigned short*)(w + alloc((size_t)768 * 256 * 2));
    int*  cnt   = (int*)(w + alloc((size_t)N * 4));
    int*  off   = (int*)(w + alloc((size_t)(N + 1) * 4));
    int*  cur   = (int*)(w + alloc((size_t)N * 4));
    int2* edges = (int2*)(w + alloc((size_t)E * 8));
    int*  last  = (int*)(w + alloc(512));
    (void)ws_size; (void)n_in; (void)out_size;

    dim3 blk(256);

    // ---- weight prep (bf16, transposed, Wl|Wr concatenated) ----
    cvt_transpose<<<DIV_UP(64 * 1024, 256), blk, 0, stream>>>(Wl1, 64, 1024, wt1);
    cvt_transpose<<<DIV_UP(64 * 1024, 256), blk, 0, stream>>>(Wr1, 64, 1024, wt1 + (size_t)1024 * 64);
    cvt_transpose<<<DIV_UP(1024 * 256, 256), blk, 0, stream>>>(Wl2, 1024, 256, wt2);
    cvt_transpose<<<DIV_UP(1024 * 256, 256), blk, 0, stream>>>(Wr2, 1024, 256, wt2 + (size_t)256 * 1024);
    cvt_transpose<<<DIV_UP(256 * 384, 256), blk, 0, stream>>>(Wlp, 256, 384, wt3);
    cvt_transpose<<<DIV_UP(256 * 384, 256), blk, 0, stream>>>(Wrp, 256, 384, wt3 + (size_t)384 * 256);
    cvt_bf16<<<DIV_UP(N * 64, 256), blk, 0, stream>>>(x, xbf, N * 64);

    // ---- CSR for edge_index (layers 1 & 2) ----
    hipMemsetAsync(cnt, 0, (size_t)N * 4, stream);
    count_kernel<<<DIV_UP(E, 256), blk, 0, stream>>>(dst1, E, cnt);
    scan_kernel<<<1, 1024, 0, stream>>>(cnt, N, off, cur);
    fill_kernel<<<DIV_UP(E, 256), blk, 0, stream>>>(src1, dst1, E, cur, edges);

    // ---- Layer 1: H=4, C=256, D=1024 ----
    gemm_mfma<<<dim3(2048 / 128, DIV_UP(N, 128)), blk, 0, stream>>>(xbf, wt1, xlr1, N, 2048, 64);
    attn_fused<4, 256, 2, true, true, true><<<DIV_UP(N, 2), blk, 0, stream>>>(
        xlr1, ea, We1, att1, edges, off, b1, h1, N);

    // ---- Layer 2: H=4, C=64, D=256 ----
    gemm_mfma<<<dim3(512 / 128, DIV_UP(N, 128)), blk, 0, stream>>>(h1, wt2, xlr2, N, 512, 1024);
    attn_fused<4, 64, 1, true, true, true><<<DIV_UP(N, 4), blk, 0, stream>>>(
        xlr2, ea, We2, att2, edges, off, b2, h2, N);

    // ---- CSR for edge_index_master (layer 3) ----
    hipMemsetAsync(cnt, 0, (size_t)N * 4, stream);
    count_kernel<<<DIV_UP(E, 256), blk, 0, stream>>>(dstm, E, cnt);
    scan_kernel<<<1, 1024, 0, stream>>>(cnt, N, off, cur);
    fill_kernel<<<DIV_UP(E, 256), blk, 0, stream>>>(srcm, dstm, E, cur, edges);

    // ---- Layer 3: H=6, C=64, D=384, no edge_attr, no relu, fp32 out ----
    gemm_mfma<<<dim3(768 / 128, DIV_UP(N, 128)), blk, 0, stream>>>(h2, wt3, xlr3, N, 768, 256);
    attn_fused<6, 64, 1, false, false, false><<<DIV_UP(N, 4), blk, 0, stream>>>(
        xlr3, nullptr, nullptr, attp, edges, off, bp, h3, N);

    // ---- head ----
    lastidx_kernel<<<1, 128, 0, stream>>>(nn, G, last);
    mlp_kernel<<<G, 64, 0, stream>>>(h3, last, Wfc1, bfc1, Wfc2, bfc2, (float*)d_out, G);
}

// Round 3
// 671.676 us; speedup vs baseline: 2.2308x; 1.1194x over previous
//
#include <hip/hip_runtime.h>
#include <hip/hip_bf16.h>

#define DIV_UP(a,b) (((a)+(b)-1)/(b))

typedef __attribute__((ext_vector_type(8))) short short8;
typedef __attribute__((ext_vector_type(4))) float floatx4;

// ---------- bf16 helpers (manual, deterministic RNE) ----------
static __device__ __forceinline__ unsigned short f2bf(float v) {
    unsigned u = __builtin_bit_cast(unsigned, v);
    u += 0x7fffu + ((u >> 16) & 1u);
    return (unsigned short)(u >> 16);
}
static __device__ __forceinline__ float bf2f(unsigned u16) {
    return __builtin_bit_cast(float, u16 << 16);
}

// load CPL bf16 -> float
template <int CPL>
static __device__ __forceinline__ void load_bf16v(const unsigned short* p, float* d) {
    if constexpr (CPL == 8) {
        uint4 v = *(const uint4*)p;
        d[0] = bf2f(v.x & 0xffffu); d[1] = bf2f(v.x >> 16);
        d[2] = bf2f(v.y & 0xffffu); d[3] = bf2f(v.y >> 16);
        d[4] = bf2f(v.z & 0xffffu); d[5] = bf2f(v.z >> 16);
        d[6] = bf2f(v.w & 0xffffu); d[7] = bf2f(v.w >> 16);
    } else if constexpr (CPL == 4) {
        uint2 v = *(const uint2*)p;
        d[0] = bf2f(v.x & 0xffffu); d[1] = bf2f(v.x >> 16);
        d[2] = bf2f(v.y & 0xffffu); d[3] = bf2f(v.y >> 16);
    } else if constexpr (CPL == 2) {
        unsigned v = *(const unsigned*)p;
        d[0] = bf2f(v & 0xffffu); d[1] = bf2f(v >> 16);
    } else {
        d[0] = bf2f(*p);
    }
}

// ---------- weight prep: W[K,N] fp32 -> Wt[N,K] bf16 ----------
__global__ void cvt_transpose(const float* __restrict__ W, int K, int Nn,
                              unsigned short* __restrict__ Wt) {
    int id = blockIdx.x * blockDim.x + threadIdx.x;
    if (id >= K * Nn) return;
    int k = id % K, n = id / K;
    Wt[(size_t)n * K + k] = f2bf(W[(size_t)k * Nn + n]);
}

__global__ void cvt_bf16(const float* __restrict__ in, unsigned short* __restrict__ out, int n) {
    int id = blockIdx.x * blockDim.x + threadIdx.x;
    if (id < n) out[id] = f2bf(in[id]);
}

// ---------- MFMA bf16 GEMM: C[M,Ntot] = A[M,K] @ Bt[Ntot,K]^T  (all bf16, fp32 acc) ----------
__global__ __launch_bounds__(256) void gemm_mfma(
    const unsigned short* __restrict__ A, const unsigned short* __restrict__ Bt,
    unsigned short* __restrict__ C, int M, int Ntot, int K) {
    constexpr int LDA = 40;  // +8 pad
    __shared__ unsigned short As[128 * LDA];
    __shared__ unsigned short Bs[128 * LDA];
    const int tid = threadIdx.x;
    const int m0 = blockIdx.y * 128, n0 = blockIdx.x * 128;
    const int wave = tid >> 6, lane = tid & 63;
    const int wm = (wave >> 1) * 64, wn = (wave & 1) * 64;
    const int r15 = lane & 15, quad = lane >> 4;
    const int sr = tid >> 1, skc = tid & 1;
    floatx4 acc[4][4];
#pragma unroll
    for (int i = 0; i < 4; ++i)
#pragma unroll
        for (int j = 0; j < 4; ++j) acc[i][j] = (floatx4)0.f;

    for (int k0 = 0; k0 < K; k0 += 32) {
        uint4 a0 = make_uint4(0, 0, 0, 0), a1 = make_uint4(0, 0, 0, 0);
        int am = m0 + sr;
        if (am < M) {
            const unsigned short* ap = A + (size_t)am * K + k0 + skc * 16;
            a0 = *(const uint4*)ap;
            a1 = *(const uint4*)(ap + 8);
        }
        const unsigned short* bp = Bt + (size_t)(n0 + sr) * K + k0 + skc * 16;
        uint4 b0 = *(const uint4*)bp;
        uint4 b1 = *(const uint4*)(bp + 8);
        *(uint4*)(&As[sr * LDA + skc * 16]) = a0;
        *(uint4*)(&As[sr * LDA + skc * 16 + 8]) = a1;
        *(uint4*)(&Bs[sr * LDA + skc * 16]) = b0;
        *(uint4*)(&Bs[sr * LDA + skc * 16 + 8]) = b1;
        __syncthreads();
        short8 af[4], bfr[4];
#pragma unroll
        for (int i = 0; i < 4; ++i)
            af[i] = *(const short8*)(&As[(wm + i * 16 + r15) * LDA + quad * 8]);
#pragma unroll
        for (int j = 0; j < 4; ++j)
            bfr[j] = *(const short8*)(&Bs[(wn + j * 16 + r15) * LDA + quad * 8]);
#pragma unroll
        for (int i = 0; i < 4; ++i)
#pragma unroll
            for (int j = 0; j < 4; ++j)
                acc[i][j] = __builtin_amdgcn_mfma_f32_16x16x32_bf16(af[i], bfr[j], acc[i][j], 0, 0, 0);
        __syncthreads();
    }
#pragma unroll
    for (int i = 0; i < 4; ++i)
#pragma unroll
        for (int j = 0; j < 4; ++j)
#pragma unroll
            for (int r = 0; r < 4; ++r) {
                int m = m0 + wm + i * 16 + quad * 4 + r;
                int n = n0 + wn + j * 16 + r15;
                if (m < M) C[(size_t)m * Ntot + n] = f2bf(acc[i][j][r]);
            }
}

// ---------- CSR build (group edges by dst) ----------
__global__ void count_kernel(const int* __restrict__ dst, int E, int* __restrict__ cnt) {
    int e = blockIdx.x * blockDim.x + threadIdx.x;
    if (e < E) atomicAdd(&cnt[dst[e]], 1);
}

__global__ __launch_bounds__(1024) void scan_kernel(const int* __restrict__ cnt, int N,
                                                    int* __restrict__ off, int* __restrict__ cur) {
    __shared__ int part[1024];
    int t = threadIdx.x;
    int per = (N + 1023) >> 10;
    int base = t * per;
    int s = 0;
    for (int i = 0; i < per; ++i) { int idx = base + i; if (idx < N) s += cnt[idx]; }
    part[t] = s;
    __syncthreads();
    for (int d2 = 1; d2 < 1024; d2 <<= 1) {
        int v = (t >= d2) ? part[t - d2] : 0;
        __syncthreads();
        part[t] += v;
        __syncthreads();
    }
    int pre = (t == 0) ? 0 : part[t - 1];
    for (int i = 0; i < per; ++i) {
        int idx = base + i;
        if (idx < N) { off[idx] = pre; cur[idx] = pre; pre += cnt[idx]; }
    }
    if (t == 1023) off[N] = part[1023];
}

__global__ void fill_kernel(const int* __restrict__ src, const int* __restrict__ dst, int E,
                            int* __restrict__ cur, int2* __restrict__ edges) {
    int e = blockIdx.x * blockDim.x + threadIdx.x;
    if (e < E) {
        int p = atomicAdd(&cur[dst[e]], 1);
        edges[p] = make_int2(src[e], e);
    }
}

// ---------- fused GATv2 edge phase: one wave per (node, head) ----------
// xlr is [N, 2D] bf16: cols [0,D) = Wl-transform (xl), [D,2D) = Wr-transform (xr).
// Lane owns CPL = C/64 contiguous channels of its head. No cross-head bookkeeping.
template <int H, int C, bool HASE, bool RELU, bool OUTBF16>
__global__ __launch_bounds__(256) void attn_fused(
    const unsigned short* __restrict__ xlr, const float* __restrict__ ea,
    const float* __restrict__ We, const float* __restrict__ att,
    const int2* __restrict__ edges, const int* __restrict__ off,
    const float* __restrict__ bias, void* __restrict__ outp, int N) {
    constexpr int D = H * C;
    constexpr int CPL = C / 64;
    const int wid = threadIdx.x >> 6, lane = threadIdx.x & 63;
    const int gw = blockIdx.x * 4 + wid;
    const int node = gw / H, head = gw - node * H;
    if (node >= N) return;
    const int c0 = head * C + lane * CPL;

    float xr_r[CPL], att_r[CPL];
    load_bf16v<CPL>(xlr + (size_t)node * (2 * D) + D + c0, xr_r);
#pragma unroll
    for (int c = 0; c < CPL; ++c) att_r[c] = att[c0 + c];
    float we_r[HASE ? 8 : 1][CPL];
    if constexpr (HASE) {
#pragma unroll
        for (int k = 0; k < 8; ++k)
#pragma unroll
            for (int c = 0; c < CPL; ++c) we_r[k][c] = We[k * D + c0 + c];
    }

    float m = -1e30f, l = 0.f, acc[CPL];
#pragma unroll
    for (int c = 0; c < CPL; ++c) acc[c] = 0.f;

    const int jb = off[node], je = off[node + 1];
    int j = jb;
    for (; j + 2 <= je; j += 2) {
        int2 e0 = edges[j], e1 = edges[j + 1];
        float xv0[CPL], xv1[CPL];
        load_bf16v<CPL>(xlr + (size_t)e0.x * (2 * D) + c0, xv0);
        load_bf16v<CPL>(xlr + (size_t)e1.x * (2 * D) + c0, xv1);
        float ev0[HASE ? 8 : 1], ev1[HASE ? 8 : 1];
        if constexpr (HASE) {
            float4 a = ((const float4*)(ea + (size_t)e0.y * 8))[0];
            float4 b = ((const float4*)(ea + (size_t)e0.y * 8))[1];
            ev0[0] = a.x; ev0[1] = a.y; ev0[2] = a.z; ev0[3] = a.w;
            ev0[4] = b.x; ev0[5] = b.y; ev0[6] = b.z; ev0[7] = b.w;
            float4 c2 = ((const float4*)(ea + (size_t)e1.y * 8))[0];
            float4 d2 = ((const float4*)(ea + (size_t)e1.y * 8))[1];
            ev1[0] = c2.x; ev1[1] = c2.y; ev1[2] = c2.z; ev1[3] = c2.w;
            ev1[4] = d2.x; ev1[5] = d2.y; ev1[6] = d2.z; ev1[7] = d2.w;
        }
        float lg0 = 0.f, lg1 = 0.f;
#pragma unroll
        for (int c = 0; c < CPL; ++c) {
            float z0 = xv0[c] + xr_r[c];
            float z1 = xv1[c] + xr_r[c];
            if constexpr (HASE) {
#pragma unroll
                for (int k = 0; k < 8; ++k) {
                    z0 = fmaf(ev0[k], we_r[k][c], z0);
                    z1 = fmaf(ev1[k], we_r[k][c], z1);
                }
            }
            z0 = z0 > 0.f ? z0 : 0.2f * z0;
            z1 = z1 > 0.f ? z1 : 0.2f * z1;
            lg0 = fmaf(att_r[c], z0, lg0);
            lg1 = fmaf(att_r[c], z1, lg1);
        }
#pragma unroll
        for (int o = 32; o; o >>= 1) {
            lg0 += __shfl_xor(lg0, o, 64);
            lg1 += __shfl_xor(lg1, o, 64);
        }
        float mn = fmaxf(m, fmaxf(lg0, lg1));
        float sc = __expf(m - mn);
        float p0 = __expf(lg0 - mn);
        float p1 = __expf(lg1 - mn);
        m = mn;
        l = fmaf(l, sc, p0 + p1);
#pragma unroll
        for (int c = 0; c < CPL; ++c)
            acc[c] = fmaf(acc[c], sc, fmaf(p0, xv0[c], p1 * xv1[c]));
    }
    if (j < je) {  // tail edge
        int2 e0 = edges[j];
        float xv0[CPL];
        load_bf16v<CPL>(xlr + (size_t)e0.x * (2 * D) + c0, xv0);
        float lg0 = 0.f;
        if constexpr (HASE) {
            float ev0[8];
            float4 a = ((const float4*)(ea + (size_t)e0.y * 8))[0];
            float4 b = ((const float4*)(ea + (size_t)e0.y * 8))[1];
            ev0[0] = a.x; ev0[1] = a.y; ev0[2] = a.z; ev0[3] = a.w;
            ev0[4] = b.x; ev0[5] = b.y; ev0[6] = b.z; ev0[7] = b.w;
#pragma unroll
            for (int c = 0; c < CPL; ++c) {
                float z = xv0[c] + xr_r[c];
#pragma unroll
                for (int k = 0; k < 8; ++k) z = fmaf(ev0[k], we_r[k][c], z);
                z = z > 0.f ? z : 0.2f * z;
                lg0 = fmaf(att_r[c], z, lg0);
            }
        } else {
#pragma unroll
            for (int c = 0; c < CPL; ++c) {
                float z = xv0[c] + xr_r[c];
                z = z > 0.f ? z : 0.2f * z;
                lg0 = fmaf(att_r[c], z, lg0);
            }
        }
#pragma unroll
        for (int o = 32; o; o >>= 1) lg0 += __shfl_xor(lg0, o, 64);
        float mn = fmaxf(m, lg0);
        float sc = __expf(m - mn);
        float p0 = __expf(lg0 - mn);
        m = mn;
        l = fmaf(l, sc, p0);
#pragma unroll
        for (int c = 0; c < CPL; ++c) acc[c] = fmaf(acc[c], sc, p0 * xv0[c]);
    }

    float inv = 1.f / (l + 1e-16f);
    if constexpr (OUTBF16) {
        unsigned short* out = (unsigned short*)outp + (size_t)node * D + c0;
        unsigned short tmp[CPL];
#pragma unroll
        for (int c = 0; c < CPL; ++c) {
            float r = fmaf(acc[c], inv, bias[c0 + c]);
            if constexpr (RELU) r = fmaxf(r, 0.f);
            tmp[c] = f2bf(r);
        }
        if constexpr (CPL == 4) *(ushort4*)out = *(ushort4*)tmp;
        else if constexpr (CPL == 2) *(ushort2*)out = *(ushort2*)tmp;
        else out[0] = tmp[0];
    } else {
        float* out = (float*)outp + (size_t)node * D + c0;
#pragma unroll
        for (int c = 0; c < CPL; ++c) {
            float r = fmaf(acc[c], inv, bias[c0 + c]);
            if constexpr (RELU) r = fmaxf(r, 0.f);
            out[c] = r;
        }
    }
}

// ---------- head: last-node gather + 2-layer MLP ----------
__global__ void lastidx_kernel(const int* __restrict__ nn, int G, int* __restrict__ last) {
    int t = blockIdx.x * blockDim.x + threadIdx.x;
    if (t < G) {
        int s = 0;
        for (int k = 0; k <= t; ++k) s += nn[k];
        last[t] = s - 1;
    }
}

__global__ void mlp_kernel(const float* __restrict__ h3, const int* __restrict__ last,
                           const float* __restrict__ Wfc1, const float* __restrict__ bfc1,
                           const float* __restrict__ Wfc2, const float* __restrict__ bfc2,
                           float* __restrict__ out, int G) {
    int g = blockIdx.x, t = threadIdx.x;  // 64 threads
    const float* row = h3 + (size_t)last[g] * 384;
    float z = bfc1[t];
    for (int k = 0; k < 384; ++k) z = fmaf(row[k], Wfc1[k * 64 + t], z);
    z = fmaxf(z, 0.f);
    float v = z * Wfc2[t];
#pragma unroll
    for (int o = 32; o; o >>= 1) v += __shfl_xor(v, o, 64);
    if (t == 0) out[g] = v + bfc2[0];
}

extern "C" void kernel_launch(void* const* d_in, const int* in_sizes, int n_in,
                              void* d_out, int out_size, void* d_ws, size_t ws_size,
                              hipStream_t stream) {
    const float* x    = (const float*)d_in[0];
    const float* ea   = (const float*)d_in[1];
    const float* Wl1  = (const float*)d_in[2];
    const float* Wr1  = (const float*)d_in[3];
    const float* We1  = (const float*)d_in[4];
    const float* att1 = (const float*)d_in[5];
    const float* b1   = (const float*)d_in[6];
    const float* Wl2  = (const float*)d_in[7];
    const float* Wr2  = (const float*)d_in[8];
    const float* We2  = (const float*)d_in[9];
    const float* att2 = (const float*)d_in[10];
    const float* b2   = (const float*)d_in[11];
    const float* Wlp  = (const float*)d_in[12];
    const float* Wrp  = (const float*)d_in[13];
    const float* attp = (const float*)d_in[14];
    const float* bp   = (const float*)d_in[15];
    const float* Wfc1 = (const float*)d_in[16];
    const float* bfc1 = (const float*)d_in[17];
    const float* Wfc2 = (const float*)d_in[18];
    const float* bfc2 = (const float*)d_in[19];
    const int* ei     = (const int*)d_in[20];
    const int* eim    = (const int*)d_in[21];
    const int* nn     = (const int*)d_in[22];

    const int N = in_sizes[0] / 64;   // 20000
    const int E = in_sizes[20] / 2;   // 160000
    const int G = in_sizes[22];       // 100
    const int* src1 = ei,  *dst1 = ei + E;
    const int* srcm = eim, *dstm = eim + E;

    // ---- workspace layout (~156 MB peak) ----
    char* w = (char*)d_ws;
    size_t o = 0;
    auto alloc = [&](size_t b) { size_t r = o; o += (b + 255) & ~(size_t)255; return r; };
    char* R1 = w + alloc((size_t)N * 2048 * 2);
    unsigned short* xlr1 = (unsigned short*)R1;
    unsigned short* xlr3 = (unsigned short*)R1;
    float* h3 = (float*)(R1 + (size_t)N * 768 * 2 + 256);
    unsigned short* h1   = (unsigned short*)(w + alloc((size_t)N * 1024 * 2));
    unsigned short* xlr2 = (unsigned short*)(w + alloc((size_t)N * 512 * 2));
    unsigned short* h2   = (unsigned short*)(w + alloc((size_t)N * 256 * 2));
    unsigned short* xbf  = (unsigned short*)(w + alloc((size_t)N * 64 * 2));
    unsigned short* wt1  = (unsigned short*)(w + alloc((size_t)2048 * 64 * 2));
    unsigned short* wt2  = (unsigned short*)(w + alloc((size_t)512 * 1024 * 2));
    unsigned short* wt3  = (unsigned short*)(w + alloc((size_t)768 * 256 * 2));
    int*  cnt   = (int*)(w + alloc((size_t)N * 4));
    int*  off   = (int*)(w + alloc((size_t)(N + 1) * 4));
    int*  cur   = (int*)(w + alloc((size_t)N * 4));
    int2* edges = (int2*)(w + alloc((size_t)E * 8));
    int*  last  = (int*)(w + alloc(512));
    (void)ws_size; (void)n_in; (void)out_size;

    dim3 blk(256);

    // ---- weight prep (bf16, transposed, Wl|Wr concatenated) ----
    cvt_transpose<<<DIV_UP(64 * 1024, 256), blk, 0, stream>>>(Wl1, 64, 1024, wt1);
    cvt_transpose<<<DIV_UP(64 * 1024, 256), blk, 0, stream>>>(Wr1, 64, 1024, wt1 + (size_t)1024 * 64);
    cvt_transpose<<<DIV_UP(1024 * 256, 256), blk, 0, stream>>>(Wl2, 1024, 256, wt2);
    cvt_transpose<<<DIV_UP(1024 * 256, 256), blk, 0, stream>>>(Wr2, 1024, 256, wt2 + (size_t)256 * 1024);
    cvt_transpose<<<DIV_UP(256 * 384, 256), blk, 0, stream>>>(Wlp, 256, 384, wt3);
    cvt_transpose<<<DIV_UP(256 * 384, 256), blk, 0, stream>>>(Wrp, 256, 384, wt3 + (size_t)384 * 256);
    cvt_bf16<<<DIV_UP(N * 64, 256), blk, 0, stream>>>(x, xbf, N * 64);

    // ---- CSR for edge_index (layers 1 & 2) ----
    hipMemsetAsync(cnt, 0, (size_t)N * 4, stream);
    count_kernel<<<DIV_UP(E, 256), blk, 0, stream>>>(dst1, E, cnt);
    scan_kernel<<<1, 1024, 0, stream>>>(cnt, N, off, cur);
    fill_kernel<<<DIV_UP(E, 256), blk, 0, stream>>>(src1, dst1, E, cur, edges);

    // ---- Layer 1: H=4, C=256, D=1024 ----
    gemm_mfma<<<dim3(2048 / 128, DIV_UP(N, 128)), blk, 0, stream>>>(xbf, wt1, xlr1, N, 2048, 64);
    attn_fused<4, 256, true, true, true><<<DIV_UP(N * 4, 4), blk, 0, stream>>>(
        xlr1, ea, We1, att1, edges, off, b1, h1, N);

    // ---- Layer 2: H=4, C=64, D=256 ----
    gemm_mfma<<<dim3(512 / 128, DIV_UP(N, 128)), blk, 0, stream>>>(h1, wt2, xlr2, N, 512, 1024);
    attn_fused<4, 64, true, true, true><<<DIV_UP(N * 4, 4), blk, 0, stream>>>(
        xlr2, ea, We2, att2, edges, off, b2, h2, N);

    // ---- CSR for edge_index_master (layer 3) ----
    hipMemsetAsync(cnt, 0, (size_t)N * 4, stream);
    count_kernel<<<DIV_UP(E, 256), blk, 0, stream>>>(dstm, E, cnt);
    scan_kernel<<<1, 1024, 0, stream>>>(cnt, N, off, cur);
    fill_kernel<<<DIV_UP(E, 256), blk, 0, stream>>>(srcm, dstm, E, cur, edges);

    // ---- Layer 3: H=6, C=64, D=384, no edge_attr, no relu, fp32 out ----
    gemm_mfma<<<dim3(768 / 128, DIV_UP(N, 128)), blk, 0, stream>>>(h2, wt3, xlr3, N, 768, 256);
    attn_fused<6, 64, false, false, false><<<DIV_UP(N * 6, 4), blk, 0, stream>>>(
        xlr3, nullptr, nullptr, attp, edges, off, bp, h3, N);

    // ---- head ----
    lastidx_kernel<<<1, 128, 0, stream>>>(nn, G, last);
    mlp_kernel<<<G, 64, 0, stream>>>(h3, last, Wfc1, bfc1, Wfc2, bfc2, (float*)d_out, G);
}